// Round 7
// baseline (499.023 us; speedup 1.0000x reference)
//
#include <hip/hip_runtime.h>
#include <math.h>

#define EMB 128
#define HIDN 256

typedef _Float16 half8 __attribute__((ext_vector_type(8)));
typedef _Float16 half4 __attribute__((ext_vector_type(4)));
typedef float f32x4 __attribute__((ext_vector_type(4)));
typedef unsigned short u16;

// ---------------- CSR build ----------------

__global__ void zero_i32(int* p, int n) {
    int i = blockIdx.x * blockDim.x + threadIdx.x;
    if (i < n) p[i] = 0;
}

__global__ void hist_kernel(const int* __restrict__ dst, int E, int* __restrict__ cnt) {
    int i = blockIdx.x * blockDim.x + threadIdx.x;
    if (i < E) atomicAdd(&cnt[dst[i]], 1);
}

__global__ void scan_partial(const int* __restrict__ cnt, int* __restrict__ partials, int Nn) {
    __shared__ int red[256];
    const int b = blockIdx.x, t = threadIdx.x;
    const int base = b * 1024 + t * 4;
    int s = 0;
#pragma unroll
    for (int i = 0; i < 4; ++i)
        if (base + i < Nn) s += cnt[base + i];
    red[t] = s;
    __syncthreads();
    for (int d = 128; d > 0; d >>= 1) {
        if (t < d) red[t] += red[t + d];
        __syncthreads();
    }
    if (t == 0) partials[b] = red[0];
}

__global__ void scan_top(int* __restrict__ partials, int nB) {
    __shared__ int s[256];
    const int t = threadIdx.x;
    int orig = (t < nB) ? partials[t] : 0;
    s[t] = orig;
    __syncthreads();
    for (int d = 1; d < 256; d <<= 1) {
        int v = (t >= d) ? s[t - d] : 0;
        __syncthreads();
        s[t] += v;
        __syncthreads();
    }
    if (t < nB) partials[t] = s[t] - orig;
}

__global__ void scan_apply(const int* __restrict__ cnt, const int* __restrict__ pbase,
                           int* __restrict__ off, int* __restrict__ cur, int Nn, int E) {
    __shared__ int tsum[256];
    const int b = blockIdx.x, t = threadIdx.x;
    const int base = b * 1024 + t * 4;
    int c[4];
#pragma unroll
    for (int i = 0; i < 4; ++i) c[i] = (base + i < Nn) ? cnt[base + i] : 0;
    int s = c[0] + c[1] + c[2] + c[3];
    tsum[t] = s;
    __syncthreads();
    for (int d = 1; d < 256; d <<= 1) {
        int v = (t >= d) ? tsum[t - d] : 0;
        __syncthreads();
        tsum[t] += v;
        __syncthreads();
    }
    int run = pbase[b] + ((t == 0) ? 0 : tsum[t - 1]);
#pragma unroll
    for (int i = 0; i < 4; ++i) {
        int idx = base + i;
        if (idx < Nn) {
            off[idx] = run;
            cur[idx] = run;
            run += c[i];
        }
    }
    if (b == 0 && t == 0) off[Nn] = E;
}

// Nn < 65536 -> u16 neighbor indices (halves index traffic; enables L2-resident slices)
__global__ void scatter_kernel(const int* __restrict__ src, const int* __restrict__ dst,
                               int E, int* __restrict__ cur, u16* __restrict__ sorted) {
    int i = blockIdx.x * blockDim.x + threadIdx.x;
    if (i < E) {
        int d = dst[i];
        int p = atomicAdd(&cur[d], 1);
        sorted[p] = (u16)src[i];
    }
}

// ---------------- prep: f32->f16, W packing ----------------

__global__ void f32_to_f16(const float* __restrict__ in, _Float16* __restrict__ out, int n4) {
    int i = blockIdx.x * blockDim.x + threadIdx.x;
    if (i < n4) {
        float4 v = *reinterpret_cast<const float4*>(in + (size_t)i * 4);
        half4 h;
        h[0] = (_Float16)v.x; h[1] = (_Float16)v.y;
        h[2] = (_Float16)v.z; h[3] = (_Float16)v.w;
        *reinterpret_cast<half4*>(out + (size_t)i * 4) = h;
    }
}

// Wg granule p = (k/8)*N + n holds f16 W[k..k+8][n].
__global__ void pack_w(const float* __restrict__ W, _Float16* __restrict__ Wg, int K, int N) {
    int p = blockIdx.x * blockDim.x + threadIdx.x;
    if (p < (K / 8) * N) {
        int j = p / N, n = p - j * N;
        half8 h;
#pragma unroll
        for (int i = 0; i < 8; ++i) h[i] = (_Float16)W[(size_t)(j * 8 + i) * N + n];
        *reinterpret_cast<half8*>(Wg + (size_t)p * 8) = h;
    }
}

// ---------------- XCD-pinned feature-sliced segment-max + self-add ----------------
// SL = K/32 slices of 32 cols (64B). slice = blockIdx % SL; with round-robin
// block->XCD dispatch, each XCD touches one slice (3.2MB) -> L2-resident.
// Block 256 thr = 4 waves; wave = 1 node; 16 edge-streams x 4 lanes (16B each).
// Output xg in MFMA granule layout: granule ((node/64)*(K/8)+j)*64 + node%64.

template <int K>
__global__ __launch_bounds__(256) void seg_sliced(
    const _Float16* __restrict__ x, const int* __restrict__ off,
    const u16* __restrict__ sorted, _Float16* __restrict__ xg, int Nn)
{
    constexpr int SL = K / 32;
    const int slice = blockIdx.x % SL;
    const int node  = (blockIdx.x / SL) * 4 + (threadIdx.x >> 6);
    const int lane  = threadIdx.x & 63;
    if (node >= Nn) return;
    const int c0  = slice * 32;
    const int g   = lane >> 2;         // edge stream 0..15
    const int sub = lane & 3;          // 16B sub-granule within 64B
    const _Float16* xcol = x + c0 + sub * 8;

    const int beg = off[node];
    const int end = off[node + 1];

    half8 acc;
#pragma unroll
    for (int i = 0; i < 8; ++i) acc[i] = (_Float16)(-INFINITY);

    for (int eb = beg; eb < end; eb += 64) {
        const int cnt = min(64, end - eb);
        int myIdx = sorted[eb + (lane < cnt ? lane : cnt - 1)];
        const int nj = (cnt + 15) >> 4;
#pragma unroll 2
        for (int j = 0; j < nj; ++j) {
            int s = __shfl(myIdx, j * 16 + g);  // slot clamped -> dup (max idempotent)
            half8 v = *reinterpret_cast<const half8*>(xcol + (size_t)s * K);
            acc = __builtin_elementwise_max(acc, v);
        }
    }

    // combine the 16 streams: xor 4,8,16,32 over 4-lane groups
    union U { half8 h; int i[4]; };
#pragma unroll
    for (int m = 4; m <= 32; m <<= 1) {
        U a, b; a.h = acc;
#pragma unroll
        for (int k = 0; k < 4; ++k) b.i[k] = __shfl_xor(a.i[k], m);
        acc = __builtin_elementwise_max(a.h, b.h);
    }

    if (lane < 4) {
        const bool hasEdges = (end > beg);
        half8 xv = *reinterpret_cast<const half8*>(x + (size_t)node * K + c0 + lane * 8);
        half8 o;
#pragma unroll
        for (int i = 0; i < 8; ++i)
            o[i] = (_Float16)((float)xv[i] + (hasEdges ? (float)acc[i] : 0.0f));
        const int j = (c0 >> 3) + lane;
        size_t gidx = ((size_t)(node >> 6) * (K / 8) + j) * 64 + (node & 63);
        *reinterpret_cast<half8*>(xg + gidx * 8) = o;
    }
}

// ---------------- LDS-free MFMA GEMM from granule layout ----------------
// Block 256 thr = 4 waves arranged RB x CB; wave tile 64x64. A granules and
// Wg granules read straight from global (L1/L2); no LDS, no barriers.

template <int K, int N, int RB, int CB, int OUT_F32, int RELU>
__global__ __launch_bounds__(256) void gemm_g(
    const _Float16* __restrict__ xg, const _Float16* __restrict__ Wg,
    const float* __restrict__ bias, void* __restrict__ C, int Nn)
{
    const int wave = threadIdx.x >> 6;
    const int lane = threadIdx.x & 63;
    const int wr = wave / CB, wc = wave % CB;
    const int rowTile = blockIdx.x * RB + wr;
    const int node0 = rowTile * 64;
    const int r  = lane & 15;
    const int gq = lane >> 4;
    const int cb = wc * 64;

    f32x4 acc[4][4];
#pragma unroll
    for (int mi = 0; mi < 4; ++mi)
#pragma unroll
        for (int ni = 0; ni < 4; ++ni) acc[mi][ni] = (f32x4){0.f, 0.f, 0.f, 0.f};

    const _Float16* Ab = xg + (size_t)rowTile * K * 64;

    for (int k0 = 0; k0 < K; k0 += 32) {
        const int jb = (k0 >> 3) + gq;
        half8 aF[4], bF[4];
#pragma unroll
        for (int mi = 0; mi < 4; ++mi)
            aF[mi] = *reinterpret_cast<const half8*>(Ab + (size_t)((jb << 6) + mi * 16 + r) * 8);
#pragma unroll
        for (int ni = 0; ni < 4; ++ni)
            bF[ni] = *reinterpret_cast<const half8*>(Wg + ((size_t)jb * N + cb + ni * 16 + r) * 8);
#pragma unroll
        for (int mi = 0; mi < 4; ++mi)
#pragma unroll
            for (int ni = 0; ni < 4; ++ni)
                acc[mi][ni] = __builtin_amdgcn_mfma_f32_16x16x32_f16(aF[mi], bF[ni], acc[mi][ni], 0, 0, 0);
    }

#pragma unroll
    for (int ni = 0; ni < 4; ++ni) {
        int colC = cb + ni * 16 + r;
        float bv = bias[colC];
#pragma unroll
        for (int mi = 0; mi < 4; ++mi) {
#pragma unroll
            for (int q = 0; q < 4; ++q) {
                int row = node0 + mi * 16 + (gq << 2) + q;
                if (row < Nn) {
                    float v = acc[mi][ni][q] + bv;
                    if (RELU) v = fmaxf(v, 0.f);
                    if (OUT_F32) ((float*)C)[(size_t)row * N + colC] = v;
                    else         ((_Float16*)C)[(size_t)row * N + colC] = (_Float16)v;
                }
            }
        }
    }
}

// ---------------- launch ----------------

extern "C" void kernel_launch(void* const* d_in, const int* in_sizes, int n_in,
                              void* d_out, int out_size, void* d_ws, size_t ws_size,
                              hipStream_t stream) {
    const int*   src = (const int*)d_in[0];
    const int*   dst = (const int*)d_in[1];
    const float* emb = (const float*)d_in[2];
    const float* W1  = (const float*)d_in[3];
    const float* b1  = (const float*)d_in[4];
    const float* W2  = (const float*)d_in[5];
    const float* b2  = (const float*)d_in[6];
    const float* W3  = (const float*)d_in[7];
    const float* b3  = (const float*)d_in[8];
    float* out = (float*)d_out;

    const int E  = in_sizes[0];
    const int Nn = in_sizes[2] / EMB;
    const int nTiles = (Nn + 63) / 64;

    char* ws = (char*)d_ws;
    auto align256 = [](size_t x) { return (x + 255) & ~(size_t)255; };
    size_t p = 0;
    int* off      = (int*)(ws + p); p = align256(p + (size_t)(Nn + 1) * 4);
    int* cur      = (int*)(ws + p); p = align256(p + (size_t)(Nn + 1) * 4);
    int* partials = (int*)(ws + p); p = align256(p + 256 * 4);
    u16* sorted   = (u16*)(ws + p); p = align256(p + (size_t)E * 2);
    _Float16* buf0 = (_Float16*)(ws + p); p = align256(p + (size_t)Nn * HIDN * 2);
    _Float16* buf1 = (_Float16*)(ws + p); p = align256(p + (size_t)Nn * HIDN * 2);
    _Float16* xg   = (_Float16*)(ws + p); p = align256(p + (size_t)nTiles * 64 * HIDN * 2);
    _Float16* Wg1  = (_Float16*)(ws + p); p = align256(p + (size_t)EMB * HIDN * 2);
    _Float16* Wg2  = (_Float16*)(ws + p); p = align256(p + (size_t)HIDN * HIDN * 2);
    _Float16* Wg3  = (_Float16*)(ws + p); p = align256(p + (size_t)HIDN * EMB * 2);

    // ---- CSR build (by dst) ----
    const int nScanBlocks = (Nn + 1023) / 1024;
    zero_i32<<<(Nn + 255) / 256, 256, 0, stream>>>(cur, Nn);
    hist_kernel<<<(E + 255) / 256, 256, 0, stream>>>(dst, E, cur);
    scan_partial<<<nScanBlocks, 256, 0, stream>>>(cur, partials, Nn);
    scan_top<<<1, 256, 0, stream>>>(partials, nScanBlocks);
    scan_apply<<<nScanBlocks, 256, 0, stream>>>(cur, partials, off, cur, Nn, E);
    scatter_kernel<<<(E + 255) / 256, 256, 0, stream>>>(src, dst, E, cur, sorted);

    // ---- weight packing + emb -> fp16 ----
    pack_w<<<(EMB / 8 * HIDN + 255) / 256, 256, 0, stream>>>(W1, Wg1, EMB, HIDN);
    pack_w<<<(HIDN / 8 * HIDN + 255) / 256, 256, 0, stream>>>(W2, Wg2, HIDN, HIDN);
    pack_w<<<(HIDN / 8 * EMB + 255) / 256, 256, 0, stream>>>(W3, Wg3, HIDN, EMB);
    f32_to_f16<<<(Nn * EMB / 4 + 255) / 256, 256, 0, stream>>>(emb, buf0, Nn * EMB / 4);

    const int nodeGroups = (Nn + 3) / 4;

    // ---- Layer 1: K=128 -> N=256, relu ----
    seg_sliced<128><<<4 * nodeGroups, 256, 0, stream>>>(buf0, off, sorted, xg, Nn);
    gemm_g<128, 256, 1, 4, 0, 1><<<nTiles, 256, 0, stream>>>(xg, Wg1, b1, buf1, Nn);

    // ---- Layer 2: K=256 -> N=256, relu ----
    seg_sliced<256><<<8 * nodeGroups, 256, 0, stream>>>(buf1, off, sorted, xg, Nn);
    gemm_g<256, 256, 1, 4, 0, 1><<<nTiles, 256, 0, stream>>>(xg, Wg2, b2, buf0, Nn);

    // ---- Layer 3: K=256 -> N=128, no relu, f32 out ----
    seg_sliced<256><<<8 * nodeGroups, 256, 0, stream>>>(buf0, off, sorted, xg, Nn);
    gemm_g<256, 128, 2, 2, 1, 0><<<(nTiles + 1) / 2, 256, 0, stream>>>(xg, Wg3, b3, out, Nn);
}

// Round 8
// 347.073 us; speedup vs baseline: 1.4378x; 1.4378x over previous
//
#include <hip/hip_runtime.h>
#include <math.h>

#define EMB 128
#define HIDN 256

typedef _Float16 half8 __attribute__((ext_vector_type(8)));
typedef _Float16 half4 __attribute__((ext_vector_type(4)));
typedef float f32x4 __attribute__((ext_vector_type(4)));
typedef unsigned short u16;

// ---------------- CSR build ----------------

__global__ void hist_kernel(const int* __restrict__ dst, int E, int* __restrict__ cnt) {
    int i = blockIdx.x * blockDim.x + threadIdx.x;
    if (i < E) atomicAdd(&cnt[dst[i]], 1);
}

__global__ void scan_partial(const int* __restrict__ cnt, int* __restrict__ partials, int Nn) {
    __shared__ int red[256];
    const int b = blockIdx.x, t = threadIdx.x;
    const int base = b * 1024 + t * 4;
    int s = 0;
#pragma unroll
    for (int i = 0; i < 4; ++i)
        if (base + i < Nn) s += cnt[base + i];
    red[t] = s;
    __syncthreads();
    for (int d = 128; d > 0; d >>= 1) {
        if (t < d) red[t] += red[t + d];
        __syncthreads();
    }
    if (t == 0) partials[b] = red[0];
}

__global__ void scan_top(int* __restrict__ partials, int nB) {
    __shared__ int s[256];
    const int t = threadIdx.x;
    int orig = (t < nB) ? partials[t] : 0;
    s[t] = orig;
    __syncthreads();
    for (int d = 1; d < 256; d <<= 1) {
        int v = (t >= d) ? s[t - d] : 0;
        __syncthreads();
        s[t] += v;
        __syncthreads();
    }
    if (t < nB) partials[t] = s[t] - orig;
}

__global__ void scan_apply(const int* __restrict__ cnt, const int* __restrict__ pbase,
                           int* __restrict__ off, int* __restrict__ cur, int Nn, int E) {
    __shared__ int tsum[256];
    const int b = blockIdx.x, t = threadIdx.x;
    const int base = b * 1024 + t * 4;
    int c[4];
#pragma unroll
    for (int i = 0; i < 4; ++i) c[i] = (base + i < Nn) ? cnt[base + i] : 0;
    int s = c[0] + c[1] + c[2] + c[3];
    tsum[t] = s;
    __syncthreads();
    for (int d = 1; d < 256; d <<= 1) {
        int v = (t >= d) ? tsum[t - d] : 0;
        __syncthreads();
        tsum[t] += v;
        __syncthreads();
    }
    int run = pbase[b] + ((t == 0) ? 0 : tsum[t - 1]);
#pragma unroll
    for (int i = 0; i < 4; ++i) {
        int idx = base + i;
        if (idx < Nn) {
            off[idx] = run;
            cur[idx] = run;
            run += c[i];
        }
    }
    if (b == 0 && t == 0) off[Nn] = E;
}

// Nn < 65536 -> u16 neighbor indices
__global__ void scatter_kernel(const int* __restrict__ src, const int* __restrict__ dst,
                               int E, int* __restrict__ cur, u16* __restrict__ sorted) {
    int i = blockIdx.x * blockDim.x + threadIdx.x;
    if (i < E) {
        int d = dst[i];
        int p = atomicAdd(&cur[d], 1);
        sorted[p] = (u16)src[i];
    }
}

// Sort each node's neighbor list ascending by src (locality only; max is
// commutative so results are bitwise identical). One wave per node, 64-lane
// bitonic network. Segments longer than 64 (vanishingly rare at Poisson(16))
// are legally left unsorted.
__global__ void sort_neighbors(const int* __restrict__ off, u16* __restrict__ sorted, int Nn) {
    const int node = blockIdx.x * 4 + (threadIdx.x >> 6);
    const int lane = threadIdx.x & 63;
    if (node >= Nn) return;
    const int beg = off[node];
    const int cnt = off[node + 1] - beg;
    if (cnt < 2 || cnt > 64) return;
    int v = (lane < cnt) ? (int)sorted[beg + lane] : 0x10000;
#pragma unroll
    for (int k = 2; k <= 64; k <<= 1) {
#pragma unroll
        for (int j = k >> 1; j > 0; j >>= 1) {
            int other = __shfl_xor(v, j);
            bool keepMin = (((lane & j) == 0) == ((lane & k) == 0));
            v = keepMin ? min(v, other) : max(v, other);
        }
    }
    if (lane < cnt) sorted[beg + lane] = (u16)v;
}

// ---------------- fused prep: zero counters + f32->f16 + W transposes ----------------
// Independent jobs packed into one launch via blockIdx ranges.

__global__ void prep_kernel(int* __restrict__ cur, int Nn,
                            const float* __restrict__ emb, _Float16* __restrict__ buf0, int n4,
                            const float* __restrict__ W1, _Float16* __restrict__ Wt1,
                            const float* __restrict__ W2, _Float16* __restrict__ Wt2,
                            const float* __restrict__ W3, _Float16* __restrict__ Wt3,
                            int bZeroEnd, int bCvtEnd, int bW1End, int bW2End, int bW3End) {
    const int b = blockIdx.x;
    const int t = threadIdx.x;
    if (b < bZeroEnd) {
        int i = b * 256 + t;
        if (i < Nn) cur[i] = 0;
    } else if (b < bCvtEnd) {
        int i = (b - bZeroEnd) * 256 + t;
        if (i < n4) {
            float4 v = *reinterpret_cast<const float4*>(emb + (size_t)i * 4);
            half4 h;
            h[0] = (_Float16)v.x; h[1] = (_Float16)v.y;
            h[2] = (_Float16)v.z; h[3] = (_Float16)v.w;
            *reinterpret_cast<half4*>(buf0 + (size_t)i * 4) = h;
        }
    } else if (b < bW1End) {
        int i = (b - bCvtEnd) * 256 + t;           // K=EMB, N=HIDN
        if (i < EMB * HIDN) {
            int k = i / HIDN, n = i - k * HIDN;
            Wt1[(size_t)n * EMB + k] = (_Float16)W1[i];
        }
    } else if (b < bW2End) {
        int i = (b - bW1End) * 256 + t;            // K=HIDN, N=HIDN
        if (i < HIDN * HIDN) {
            int k = i / HIDN, n = i - k * HIDN;
            Wt2[(size_t)n * HIDN + k] = (_Float16)W2[i];
        }
    } else if (b < bW3End) {
        int i = (b - bW2End) * 256 + t;            // K=HIDN, N=EMB
        if (i < HIDN * EMB) {
            int k = i / EMB, n = i - k * EMB;
            Wt3[(size_t)n * HIDN + k] = (_Float16)W3[i];
        }
    }
}

// ---------------- fused segment-max + self-add (fp16, packed max) ----------------
// One wave per node. Lane holds half8 (16B). NG edge streams per wave.

template <int VEC>
__global__ void segmax_add_h(const _Float16* __restrict__ x, const int* __restrict__ off,
                             const u16* __restrict__ sorted, _Float16* __restrict__ xs, int Nn) {
    const int D = VEC * 64;
    const int NG = (VEC == 4) ? 2 : 4;   // concurrent edge streams
    const int LPR = 64 / NG;             // lanes per row
    const int node = blockIdx.x * (blockDim.x >> 6) + (threadIdx.x >> 6);
    const int lane = threadIdx.x & 63;
    if (node >= Nn) return;
    const int g = lane / LPR;
    const int col = (lane % LPR) * 8;
    const int beg = off[node];
    const int end = off[node + 1];
    const _Float16* xcol = x + col;

    half8 acc;
#pragma unroll
    for (int i = 0; i < 8; ++i) acc[i] = (_Float16)(-INFINITY);

    for (int eb = beg; eb < end; eb += 64) {
        const int cnt = min(64, end - eb);
        int myIdx = sorted[eb + (lane < cnt ? lane : cnt - 1)];
        const int nj = (cnt + NG - 1) / NG;
#pragma unroll 4
        for (int j = 0; j < nj; ++j) {
            int s = __shfl(myIdx, j * NG + g);
            half8 v = *reinterpret_cast<const half8*>(xcol + (size_t)s * D);
            acc = __builtin_elementwise_max(acc, v);
        }
    }

    union U { half8 h; int i[4]; };
    if (NG == 4) {
        U a, b; a.h = acc;
#pragma unroll
        for (int k = 0; k < 4; ++k) b.i[k] = __shfl_xor(a.i[k], 16);
        acc = __builtin_elementwise_max(a.h, b.h);
    }
    {
        U a, b; a.h = acc;
#pragma unroll
        for (int k = 0; k < 4; ++k) b.i[k] = __shfl_xor(a.i[k], 32);
        acc = __builtin_elementwise_max(a.h, b.h);
    }

    if (g == 0) {
        const bool hasEdges = (end > beg);
        half8 xv = *reinterpret_cast<const half8*>(xcol + (size_t)node * D);
        half8 o;
#pragma unroll
        for (int i = 0; i < 8; ++i)
            o[i] = (_Float16)((float)xv[i] + (hasEdges ? (float)acc[i] : 0.0f));
        *reinterpret_cast<half8*>(xs + (size_t)node * D + col) = o;
    }
}

// ---------------- MFMA fp16 GEMM ----------------
// C[M,N] = A[M,K] @ W[K,N] + bias (+ReLU). A fp16 row-major, Wt fp16 [N][K].
// BM=128, BN=128, BK=32. 256 threads = 4 waves (2x2), each wave 64x64 out.

template <int OUT_F32, int RELU>
__global__ __launch_bounds__(256) void gemm_h(
    const _Float16* __restrict__ A, const _Float16* __restrict__ Wt,
    const float* __restrict__ bias, void* __restrict__ C,
    int M, int K, int N)
{
    __shared__ _Float16 sA[4 * 128 * 8];
    __shared__ _Float16 sB[4 * 128 * 8];

    const int tid = threadIdx.x;
    const int r0 = blockIdx.x * 128;
    const int n0 = blockIdx.y * 128;

    const int wave = tid >> 6;
    const int lane = tid & 63;
    const int g = lane >> 4;
    const int r = lane & 15;
    const int m_base = (wave >> 1) * 64;
    const int n_base = (wave & 1) * 64;

    f32x4 acc[4][4];
#pragma unroll
    for (int i = 0; i < 4; ++i)
#pragma unroll
        for (int j = 0; j < 4; ++j) acc[i][j] = (f32x4){0.f, 0.f, 0.f, 0.f};

    for (int k0 = 0; k0 < K; k0 += 32) {
#pragma unroll
        for (int h = 0; h < 2; ++h) {
            int s = tid + h * 256;
            int row = s >> 2;
            int j = s & 3;
            int ar = r0 + row; ar = ar < M ? ar : (M - 1);
            half8 av = *reinterpret_cast<const half8*>(A + (size_t)ar * K + k0 + j * 8);
            *reinterpret_cast<half8*>(&sA[((j << 7) + row) << 3]) = av;
            half8 bv = *reinterpret_cast<const half8*>(Wt + (size_t)(n0 + row) * K + k0 + j * 8);
            *reinterpret_cast<half8*>(&sB[((j << 7) + row) << 3]) = bv;
        }
        __syncthreads();

        half8 aF[4], bF[4];
#pragma unroll
        for (int mi = 0; mi < 4; ++mi)
            aF[mi] = *reinterpret_cast<half8*>(&sA[((g << 7) + m_base + mi * 16 + r) << 3]);
#pragma unroll
        for (int ni = 0; ni < 4; ++ni)
            bF[ni] = *reinterpret_cast<half8*>(&sB[((g << 7) + n_base + ni * 16 + r) << 3]);

#pragma unroll
        for (int mi = 0; mi < 4; ++mi)
#pragma unroll
            for (int ni = 0; ni < 4; ++ni)
                acc[mi][ni] = __builtin_amdgcn_mfma_f32_16x16x32_f16(aF[mi], bF[ni], acc[mi][ni], 0, 0, 0);

        __syncthreads();
    }

#pragma unroll
    for (int ni = 0; ni < 4; ++ni) {
        int col = n0 + n_base + ni * 16 + r;
        float bv = bias[col];
#pragma unroll
        for (int mi = 0; mi < 4; ++mi) {
#pragma unroll
            for (int q = 0; q < 4; ++q) {
                int row = r0 + m_base + mi * 16 + g * 4 + q;
                if (row < M) {
                    float v = acc[mi][ni][q] + bv;
                    if (RELU) v = fmaxf(v, 0.f);
                    if (OUT_F32)
                        ((float*)C)[(size_t)row * N + col] = v;
                    else
                        ((_Float16*)C)[(size_t)row * N + col] = (_Float16)v;
                }
            }
        }
    }
}

// ---------------- launch ----------------

extern "C" void kernel_launch(void* const* d_in, const int* in_sizes, int n_in,
                              void* d_out, int out_size, void* d_ws, size_t ws_size,
                              hipStream_t stream) {
    const int*   src = (const int*)d_in[0];
    const int*   dst = (const int*)d_in[1];
    const float* emb = (const float*)d_in[2];
    const float* W1  = (const float*)d_in[3];
    const float* b1  = (const float*)d_in[4];
    const float* W2  = (const float*)d_in[5];
    const float* b2  = (const float*)d_in[6];
    const float* W3  = (const float*)d_in[7];
    const float* b3  = (const float*)d_in[8];
    float* out = (float*)d_out;

    const int E  = in_sizes[0];
    const int Nn = in_sizes[2] / EMB;

    char* ws = (char*)d_ws;
    auto align256 = [](size_t x) { return (x + 255) & ~(size_t)255; };
    size_t p = 0;
    int* off      = (int*)(ws + p); p = align256(p + (size_t)(Nn + 1) * 4);
    int* cur      = (int*)(ws + p); p = align256(p + (size_t)(Nn + 1) * 4);
    int* partials = (int*)(ws + p); p = align256(p + 256 * 4);
    u16* sorted   = (u16*)(ws + p); p = align256(p + (size_t)E * 2);
    _Float16* buf0 = (_Float16*)(ws + p); p = align256(p + (size_t)Nn * HIDN * 2);
    _Float16* buf1 = (_Float16*)(ws + p); p = align256(p + (size_t)Nn * HIDN * 2);
    _Float16* Wt1  = (_Float16*)(ws + p); p = align256(p + (size_t)EMB * HIDN * 2);
    _Float16* Wt2  = (_Float16*)(ws + p); p = align256(p + (size_t)HIDN * HIDN * 2);
    _Float16* Wt3  = (_Float16*)(ws + p); p = align256(p + (size_t)HIDN * EMB * 2);

    // ---- fused prep: zero cur + emb->f16 + W transposes ----
    const int n4 = Nn * EMB / 4;
    const int bZeroEnd = (Nn + 255) / 256;
    const int bCvtEnd  = bZeroEnd + (n4 + 255) / 256;
    const int bW1End   = bCvtEnd + (EMB * HIDN + 255) / 256;
    const int bW2End   = bW1End + (HIDN * HIDN + 255) / 256;
    const int bW3End   = bW2End + (HIDN * EMB + 255) / 256;
    prep_kernel<<<bW3End, 256, 0, stream>>>(cur, Nn, emb, buf0, n4,
                                            W1, Wt1, W2, Wt2, W3, Wt3,
                                            bZeroEnd, bCvtEnd, bW1End, bW2End, bW3End);

    // ---- CSR build (by dst) ----
    const int nScanBlocks = (Nn + 1023) / 1024;
    hist_kernel<<<(E + 255) / 256, 256, 0, stream>>>(dst, E, cur);
    scan_partial<<<nScanBlocks, 256, 0, stream>>>(cur, partials, Nn);
    scan_top<<<1, 256, 0, stream>>>(partials, nScanBlocks);
    scan_apply<<<nScanBlocks, 256, 0, stream>>>(cur, partials, off, cur, Nn, E);
    scatter_kernel<<<(E + 255) / 256, 256, 0, stream>>>(src, dst, E, cur, sorted);

    const int segBlocks = (Nn + 3) / 4;
    sort_neighbors<<<segBlocks, 256, 0, stream>>>(off, sorted, Nn);

    const int gmM = (Nn + 127) / 128;

    // ---- Layer 1: 128 -> 256, relu ----
    segmax_add_h<2><<<segBlocks, 256, 0, stream>>>(buf0, off, sorted, buf1, Nn);
    gemm_h<0, 1><<<dim3(gmM, 2), 256, 0, stream>>>(buf1, Wt1, b1, buf0, Nn, EMB, HIDN);

    // ---- Layer 2: 256 -> 256, relu ----
    segmax_add_h<4><<<segBlocks, 256, 0, stream>>>(buf0, off, sorted, buf1, Nn);
    gemm_h<0, 1><<<dim3(gmM, 2), 256, 0, stream>>>(buf1, Wt2, b2, buf0, Nn, HIDN, HIDN);

    // ---- Layer 3: 256 -> 128, no relu ----
    segmax_add_h<4><<<segBlocks, 256, 0, stream>>>(buf0, off, sorted, buf1, Nn);
    gemm_h<1, 0><<<dim3(gmM, 1), 256, 0, stream>>>(buf1, Wt3, b3, out, Nn, HIDN, EMB);
}

// Round 9
// 303.901 us; speedup vs baseline: 1.6421x; 1.1421x over previous
//
#include <hip/hip_runtime.h>
#include <math.h>

#define EMB 128
#define HIDN 256

typedef _Float16 half8 __attribute__((ext_vector_type(8)));
typedef _Float16 half4 __attribute__((ext_vector_type(4)));
typedef float f32x4 __attribute__((ext_vector_type(4)));
typedef unsigned short u16;

// ---------------- CSR build ----------------

__global__ void hist_kernel(const int* __restrict__ dst, int E, int* __restrict__ cnt) {
    int i = blockIdx.x * blockDim.x + threadIdx.x;
    if (i < E) atomicAdd(&cnt[dst[i]], 1);
}

__global__ void scan_partial(const int* __restrict__ cnt, int* __restrict__ partials, int Nn) {
    __shared__ int red[256];
    const int b = blockIdx.x, t = threadIdx.x;
    const int base = b * 1024 + t * 4;
    int s = 0;
#pragma unroll
    for (int i = 0; i < 4; ++i)
        if (base + i < Nn) s += cnt[base + i];
    red[t] = s;
    __syncthreads();
    for (int d = 128; d > 0; d >>= 1) {
        if (t < d) red[t] += red[t + d];
        __syncthreads();
    }
    if (t == 0) partials[b] = red[0];
}

__global__ void scan_top(int* __restrict__ partials, int nB) {
    __shared__ int s[256];
    const int t = threadIdx.x;
    int orig = (t < nB) ? partials[t] : 0;
    s[t] = orig;
    __syncthreads();
    for (int d = 1; d < 256; d <<= 1) {
        int v = (t >= d) ? s[t - d] : 0;
        __syncthreads();
        s[t] += v;
        __syncthreads();
    }
    if (t < nB) partials[t] = s[t] - orig;
}

__global__ void scan_apply(const int* __restrict__ cnt, const int* __restrict__ pbase,
                           int* __restrict__ off, int* __restrict__ cur, int Nn, int E) {
    __shared__ int tsum[256];
    const int b = blockIdx.x, t = threadIdx.x;
    const int base = b * 1024 + t * 4;
    int c[4];
#pragma unroll
    for (int i = 0; i < 4; ++i) c[i] = (base + i < Nn) ? cnt[base + i] : 0;
    int s = c[0] + c[1] + c[2] + c[3];
    tsum[t] = s;
    __syncthreads();
    for (int d = 1; d < 256; d <<= 1) {
        int v = (t >= d) ? tsum[t - d] : 0;
        __syncthreads();
        tsum[t] += v;
        __syncthreads();
    }
    int run = pbase[b] + ((t == 0) ? 0 : tsum[t - 1]);
#pragma unroll
    for (int i = 0; i < 4; ++i) {
        int idx = base + i;
        if (idx < Nn) {
            off[idx] = run;
            cur[idx] = run;
            run += c[i];
        }
    }
    if (b == 0 && t == 0) off[Nn] = E;
}

// Nn < 65536 -> u16 neighbor indices
__global__ void scatter_kernel(const int* __restrict__ src, const int* __restrict__ dst,
                               int E, int* __restrict__ cur, u16* __restrict__ sorted) {
    int i = blockIdx.x * blockDim.x + threadIdx.x;
    if (i < E) {
        int d = dst[i];
        int p = atomicAdd(&cur[d], 1);
        sorted[p] = (u16)src[i];
    }
}

// ---------------- fused prep: zero counters + f32->f16 + W granule packing ----------------
// Wg granule p = (k/8)*N + n holds f16 W[k..k+8][n] (contiguous half8).

__device__ __forceinline__ void pack_w_one(const float* __restrict__ W, _Float16* __restrict__ Wg,
                                           int K, int N, int i) {
    if (i < (K / 8) * N) {
        int j = i / N, n = i - j * N;
        half8 h;
#pragma unroll
        for (int q = 0; q < 8; ++q) h[q] = (_Float16)W[(size_t)(j * 8 + q) * N + n];
        *reinterpret_cast<half8*>(Wg + (size_t)i * 8) = h;
    }
}

__global__ void prep_kernel(int* __restrict__ cur, int Nn,
                            const float* __restrict__ emb, _Float16* __restrict__ buf0, int n4,
                            const float* __restrict__ W1, _Float16* __restrict__ Wg1,
                            const float* __restrict__ W2, _Float16* __restrict__ Wg2,
                            const float* __restrict__ W3, _Float16* __restrict__ Wg3,
                            int bZeroEnd, int bCvtEnd, int bW1End, int bW2End, int bW3End) {
    const int b = blockIdx.x;
    const int t = threadIdx.x;
    if (b < bZeroEnd) {
        int i = b * 256 + t;
        if (i < Nn) cur[i] = 0;
    } else if (b < bCvtEnd) {
        int i = (b - bZeroEnd) * 256 + t;
        if (i < n4) {
            float4 v = *reinterpret_cast<const float4*>(emb + (size_t)i * 4);
            half4 h;
            h[0] = (_Float16)v.x; h[1] = (_Float16)v.y;
            h[2] = (_Float16)v.z; h[3] = (_Float16)v.w;
            *reinterpret_cast<half4*>(buf0 + (size_t)i * 4) = h;
        }
    } else if (b < bW1End) {
        pack_w_one(W1, Wg1, EMB, HIDN, (b - bCvtEnd) * 256 + t);
    } else if (b < bW2End) {
        pack_w_one(W2, Wg2, HIDN, HIDN, (b - bW1End) * 256 + t);
    } else if (b < bW3End) {
        pack_w_one(W3, Wg3, HIDN, EMB, (b - bW2End) * 256 + t);
    }
}

// ---------------- segment-max + self-add -> MFMA granule layout ----------------
// One wave per node. NG = 512/K edge streams; each stream's LPR lanes read the
// SAME sorted[e] (HW same-address broadcast, L1-cached line) -> no shfl in the
// inner loop, no batching. Output granule ((node/64)*(K/8)+j)*64 + node%64.

template <int K>
__global__ __launch_bounds__(256) void segmax_g(
    const _Float16* __restrict__ x, const int* __restrict__ off,
    const u16* __restrict__ sorted, _Float16* __restrict__ xg, int Nn)
{
    constexpr int NG = 512 / K;        // 2 for K=256, 4 for K=128
    constexpr int LPR = 64 / NG;       // lanes per row
    const int node = blockIdx.x * 4 + (threadIdx.x >> 6);
    const int lane = threadIdx.x & 63;
    if (node >= Nn) return;
    const int g = lane / LPR;
    const int colh = (lane % LPR) * 8;
    const int beg = off[node];
    const int end = off[node + 1];
    const _Float16* xcol = x + colh;

    half8 acc;
#pragma unroll
    for (int i = 0; i < 8; ++i) acc[i] = (_Float16)(-INFINITY);

#pragma unroll 4
    for (int e = beg + g; e < end; e += NG) {
        int s = (int)sorted[e];
        half8 v = *reinterpret_cast<const half8*>(xcol + (size_t)s * K);
        acc = __builtin_elementwise_max(acc, v);
    }

    // combine edge streams (lanes with same colh)
    union U { half8 h; int i[4]; };
    if (NG == 4) {
        U a, b; a.h = acc;
#pragma unroll
        for (int k = 0; k < 4; ++k) b.i[k] = __shfl_xor(a.i[k], 16);
        acc = __builtin_elementwise_max(a.h, b.h);
    }
    {
        U a, b; a.h = acc;
#pragma unroll
        for (int k = 0; k < 4; ++k) b.i[k] = __shfl_xor(a.i[k], 32);
        acc = __builtin_elementwise_max(a.h, b.h);
    }

    if (g == 0) {
        const bool hasEdges = (end > beg);
        half8 xv = *reinterpret_cast<const half8*>(x + (size_t)node * K + colh);
        half8 o;
#pragma unroll
        for (int i = 0; i < 8; ++i)
            o[i] = (_Float16)((float)xv[i] + (hasEdges ? (float)acc[i] : 0.0f));
        const int j = lane;            // = colh/8, lane in [0, K/8)
        size_t gidx = ((size_t)(node >> 6) * (K / 8) + j) * 64 + (node & 63);
        *reinterpret_cast<half8*>(xg + gidx * 8) = o;
    }
}

// ---------------- LDS-free MFMA GEMM from granule layout ----------------
// Block 256 thr = 4 waves arranged RB x CB; wave tile 64x64. A granules and
// Wg granules read straight from global (L1/L2); no LDS, no barriers.

template <int K, int N, int RB, int CB, int OUT_F32, int RELU>
__global__ __launch_bounds__(256) void gemm_g(
    const _Float16* __restrict__ xg, const _Float16* __restrict__ Wg,
    const float* __restrict__ bias, void* __restrict__ C, int Nn)
{
    const int wave = threadIdx.x >> 6;
    const int lane = threadIdx.x & 63;
    const int wr = wave / CB, wc = wave % CB;
    const int rowTile = blockIdx.x * RB + wr;
    const int node0 = rowTile * 64;
    const int r  = lane & 15;
    const int gq = lane >> 4;
    const int cb = wc * 64;

    f32x4 acc[4][4];
#pragma unroll
    for (int mi = 0; mi < 4; ++mi)
#pragma unroll
        for (int ni = 0; ni < 4; ++ni) acc[mi][ni] = (f32x4){0.f, 0.f, 0.f, 0.f};

    const _Float16* Ab = xg + (size_t)rowTile * K * 64;

    for (int k0 = 0; k0 < K; k0 += 32) {
        const int jb = (k0 >> 3) + gq;
        half8 aF[4], bF[4];
#pragma unroll
        for (int mi = 0; mi < 4; ++mi)
            aF[mi] = *reinterpret_cast<const half8*>(Ab + (size_t)((jb << 6) + mi * 16 + r) * 8);
#pragma unroll
        for (int ni = 0; ni < 4; ++ni)
            bF[ni] = *reinterpret_cast<const half8*>(Wg + ((size_t)jb * N + cb + ni * 16 + r) * 8);
#pragma unroll
        for (int mi = 0; mi < 4; ++mi)
#pragma unroll
            for (int ni = 0; ni < 4; ++ni)
                acc[mi][ni] = __builtin_amdgcn_mfma_f32_16x16x32_f16(aF[mi], bF[ni], acc[mi][ni], 0, 0, 0);
    }

#pragma unroll
    for (int ni = 0; ni < 4; ++ni) {
        int colC = cb + ni * 16 + r;
        float bv = bias[colC];
#pragma unroll
        for (int mi = 0; mi < 4; ++mi) {
#pragma unroll
            for (int q = 0; q < 4; ++q) {
                int row = node0 + mi * 16 + (gq << 2) + q;
                if (row < Nn) {
                    float v = acc[mi][ni][q] + bv;
                    if (RELU) v = fmaxf(v, 0.f);
                    if (OUT_F32) ((float*)C)[(size_t)row * N + colC] = v;
                    else         ((_Float16*)C)[(size_t)row * N + colC] = (_Float16)v;
                }
            }
        }
    }
}

// ---------------- launch ----------------

extern "C" void kernel_launch(void* const* d_in, const int* in_sizes, int n_in,
                              void* d_out, int out_size, void* d_ws, size_t ws_size,
                              hipStream_t stream) {
    const int*   src = (const int*)d_in[0];
    const int*   dst = (const int*)d_in[1];
    const float* emb = (const float*)d_in[2];
    const float* W1  = (const float*)d_in[3];
    const float* b1  = (const float*)d_in[4];
    const float* W2  = (const float*)d_in[5];
    const float* b2  = (const float*)d_in[6];
    const float* W3  = (const float*)d_in[7];
    const float* b3  = (const float*)d_in[8];
    float* out = (float*)d_out;

    const int E  = in_sizes[0];
    const int Nn = in_sizes[2] / EMB;
    const int nTiles = (Nn + 63) / 64;

    char* ws = (char*)d_ws;
    auto align256 = [](size_t x) { return (x + 255) & ~(size_t)255; };
    size_t p = 0;
    int* off      = (int*)(ws + p); p = align256(p + (size_t)(Nn + 1) * 4);
    int* cur      = (int*)(ws + p); p = align256(p + (size_t)(Nn + 1) * 4);
    int* partials = (int*)(ws + p); p = align256(p + 256 * 4);
    u16* sorted   = (u16*)(ws + p); p = align256(p + (size_t)E * 2);
    _Float16* buf0 = (_Float16*)(ws + p); p = align256(p + (size_t)Nn * HIDN * 2);
    _Float16* buf1 = (_Float16*)(ws + p); p = align256(p + (size_t)Nn * HIDN * 2);
    _Float16* xg   = (_Float16*)(ws + p); p = align256(p + (size_t)(nTiles + 2) * 64 * HIDN * 2);
    _Float16* Wg1  = (_Float16*)(ws + p); p = align256(p + (size_t)EMB * HIDN * 2);
    _Float16* Wg2  = (_Float16*)(ws + p); p = align256(p + (size_t)HIDN * HIDN * 2);
    _Float16* Wg3  = (_Float16*)(ws + p); p = align256(p + (size_t)HIDN * EMB * 2);

    // ---- fused prep: zero cur + emb->f16 + W granule packing ----
    const int n4 = Nn * EMB / 4;
    const int bZeroEnd = (Nn + 255) / 256;
    const int bCvtEnd  = bZeroEnd + (n4 + 255) / 256;
    const int bW1End   = bCvtEnd + (EMB / 8 * HIDN + 255) / 256;
    const int bW2End   = bW1End + (HIDN / 8 * HIDN + 255) / 256;
    const int bW3End   = bW2End + (HIDN / 8 * EMB + 255) / 256;
    prep_kernel<<<bW3End, 256, 0, stream>>>(cur, Nn, emb, buf0, n4,
                                            W1, Wg1, W2, Wg2, W3, Wg3,
                                            bZeroEnd, bCvtEnd, bW1End, bW2End, bW3End);

    // ---- CSR build (by dst) ----
    const int nScanBlocks = (Nn + 1023) / 1024;
    hist_kernel<<<(E + 255) / 256, 256, 0, stream>>>(dst, E, cur);
    scan_partial<<<nScanBlocks, 256, 0, stream>>>(cur, partials, Nn);
    scan_top<<<1, 256, 0, stream>>>(partials, nScanBlocks);
    scan_apply<<<nScanBlocks, 256, 0, stream>>>(cur, partials, off, cur, Nn, E);
    scatter_kernel<<<(E + 255) / 256, 256, 0, stream>>>(src, dst, E, cur, sorted);

    const int segBlocks = (Nn + 3) / 4;

    // ---- Layer 1: K=128 -> N=256, relu ----
    segmax_g<128><<<segBlocks, 256, 0, stream>>>(buf0, off, sorted, xg, Nn);
    gemm_g<128, 256, 1, 4, 0, 1><<<nTiles, 256, 0, stream>>>(xg, Wg1, b1, buf1, Nn);

    // ---- Layer 2: K=256 -> N=256, relu ----
    segmax_g<256><<<segBlocks, 256, 0, stream>>>(buf1, off, sorted, xg, Nn);
    gemm_g<256, 256, 1, 4, 0, 1><<<nTiles, 256, 0, stream>>>(xg, Wg2, b2, buf0, Nn);

    // ---- Layer 3: K=256 -> N=128, no relu, f32 out ----
    segmax_g<256><<<segBlocks, 256, 0, stream>>>(buf0, off, sorted, xg, Nn);
    gemm_g<256, 128, 2, 2, 1, 0><<<(nTiles + 1) / 2, 256, 0, stream>>>(xg, Wg3, b3, out, Nn);
}

// Round 10
// 303.329 us; speedup vs baseline: 1.6452x; 1.0019x over previous
//
#include <hip/hip_runtime.h>
#include <math.h>

#define EMB 128
#define HIDN 256

typedef _Float16 half8 __attribute__((ext_vector_type(8)));
typedef _Float16 half4 __attribute__((ext_vector_type(4)));
typedef float f32x4 __attribute__((ext_vector_type(4)));
typedef unsigned short u16;

// ---------------- fused prep: f32->f16 + W granule packing + hist ----------------
// cur must be zeroed (hipMemsetAsync) before this kernel. Independent jobs
// packed into one launch via blockIdx ranges; hist's atomics overlap with the
// BW-bound convert/pack work.

__device__ __forceinline__ void pack_w_one(const float* __restrict__ W, _Float16* __restrict__ Wg,
                                           int K, int N, int i) {
    if (i < (K / 8) * N) {
        int j = i / N, n = i - j * N;
        half8 h;
#pragma unroll
        for (int q = 0; q < 8; ++q) h[q] = (_Float16)W[(size_t)(j * 8 + q) * N + n];
        *reinterpret_cast<half8*>(Wg + (size_t)i * 8) = h;
    }
}

__global__ void prep_kernel(const int* __restrict__ dst, int E, int* __restrict__ cur,
                            const float* __restrict__ emb, _Float16* __restrict__ buf0, int n4,
                            const float* __restrict__ W1, _Float16* __restrict__ Wg1,
                            const float* __restrict__ W2, _Float16* __restrict__ Wg2,
                            const float* __restrict__ W3, _Float16* __restrict__ Wg3,
                            int bCvtEnd, int bHistEnd, int bW1End, int bW2End, int bW3End) {
    const int b = blockIdx.x;
    const int t = threadIdx.x;
    if (b < bCvtEnd) {
        int i = b * 256 + t;
        if (i < n4) {
            float4 v = *reinterpret_cast<const float4*>(emb + (size_t)i * 4);
            half4 h;
            h[0] = (_Float16)v.x; h[1] = (_Float16)v.y;
            h[2] = (_Float16)v.z; h[3] = (_Float16)v.w;
            *reinterpret_cast<half4*>(buf0 + (size_t)i * 4) = h;
        }
    } else if (b < bHistEnd) {
        int i = (b - bCvtEnd) * 256 + t;
        if (i < E) atomicAdd(&cur[dst[i]], 1);
    } else if (b < bW1End) {
        pack_w_one(W1, Wg1, EMB, HIDN, (b - bHistEnd) * 256 + t);
    } else if (b < bW2End) {
        pack_w_one(W2, Wg2, HIDN, HIDN, (b - bW1End) * 256 + t);
    } else if (b < bW3End) {
        pack_w_one(W3, Wg3, HIDN, EMB, (b - bW2End) * 256 + t);
    }
}

// ---------------- hierarchical scan (2 kernels) ----------------

__global__ void scan_partial(const int* __restrict__ cnt, int* __restrict__ partials, int Nn) {
    __shared__ int red[256];
    const int b = blockIdx.x, t = threadIdx.x;
    const int base = b * 1024 + t * 4;
    int s = 0;
#pragma unroll
    for (int i = 0; i < 4; ++i)
        if (base + i < Nn) s += cnt[base + i];
    red[t] = s;
    __syncthreads();
    for (int d = 128; d > 0; d >>= 1) {
        if (t < d) red[t] += red[t + d];
        __syncthreads();
    }
    if (t == 0) partials[b] = red[0];
}

// per-block inline top-scan of partials (nB <= 64), then local scan + emit.
__global__ void scan_apply(const int* __restrict__ cnt, const int* __restrict__ partials,
                           int nB, int* __restrict__ off, int* __restrict__ cur, int Nn, int E) {
    __shared__ int tsum[256];
    __shared__ int sbase;
    const int b = blockIdx.x, t = threadIdx.x;
    if (t < 64) {
        int v = (t < b && t < nB) ? partials[t] : 0;
#pragma unroll
        for (int m = 1; m < 64; m <<= 1) v += __shfl_xor(v, m);
        if (t == 0) sbase = v;
    }
    const int base = b * 1024 + t * 4;
    int c[4];
#pragma unroll
    for (int i = 0; i < 4; ++i) c[i] = (base + i < Nn) ? cnt[base + i] : 0;
    int s = c[0] + c[1] + c[2] + c[3];
    tsum[t] = s;
    __syncthreads();
    for (int d = 1; d < 256; d <<= 1) {
        int v = (t >= d) ? tsum[t - d] : 0;
        __syncthreads();
        tsum[t] += v;
        __syncthreads();
    }
    int run = sbase + ((t == 0) ? 0 : tsum[t - 1]);
#pragma unroll
    for (int i = 0; i < 4; ++i) {
        int idx = base + i;
        if (idx < Nn) {
            off[idx] = run;
            cur[idx] = run;
            run += c[i];
        }
    }
    if (b == 0 && t == 0) off[Nn] = E;
}

// Nn < 65536 -> u16 neighbor indices
__global__ void scatter_kernel(const int* __restrict__ src, const int* __restrict__ dst,
                               int E, int* __restrict__ cur, u16* __restrict__ sorted) {
    int i = blockIdx.x * blockDim.x + threadIdx.x;
    if (i < E) {
        int d = dst[i];
        int p = atomicAdd(&cur[d], 1);
        sorted[p] = (u16)src[i];
    }
}

// ---------------- segment-max + self-add -> MFMA granule layout ----------------
// One wave per node (block = 4 waves = 4 nodes). NG = 512/K edge streams;
// stream lanes read the SAME sorted[e] (HW same-address broadcast). Result is
// block-transposed through 2KB LDS so xg granule stores are full 64B lines.

template <int K>
__global__ __launch_bounds__(256) void segmax_g(
    const _Float16* __restrict__ x, const int* __restrict__ off,
    const u16* __restrict__ sorted, _Float16* __restrict__ xg, int Nn)
{
    constexpr int NG = 512 / K;        // 2 for K=256, 4 for K=128
    constexpr int LPR = 64 / NG;       // lanes per row
    __shared__ _Float16 sm[4][K];

    const int wave = threadIdx.x >> 6;
    const int lane = threadIdx.x & 63;
    const int node0 = blockIdx.x * 4;
    const int node = node0 + wave;

    if (node < Nn) {
        const int g = lane / LPR;
        const int colh = (lane % LPR) * 8;
        const int beg = off[node];
        const int end = off[node + 1];
        const _Float16* xcol = x + colh;

        half8 acc;
#pragma unroll
        for (int i = 0; i < 8; ++i) acc[i] = (_Float16)(-INFINITY);

#pragma unroll 8
        for (int e = beg + g; e < end; e += NG) {
            int s = (int)sorted[e];
            half8 v = *reinterpret_cast<const half8*>(xcol + (size_t)s * K);
            acc = __builtin_elementwise_max(acc, v);
        }

        // combine edge streams (lanes with same colh)
        union U { half8 h; int i[4]; };
        if (NG == 4) {
            U a, b; a.h = acc;
#pragma unroll
            for (int k = 0; k < 4; ++k) b.i[k] = __shfl_xor(a.i[k], 16);
            acc = __builtin_elementwise_max(a.h, b.h);
        }
        {
            U a, b; a.h = acc;
#pragma unroll
            for (int k = 0; k < 4; ++k) b.i[k] = __shfl_xor(a.i[k], 32);
            acc = __builtin_elementwise_max(a.h, b.h);
        }

        if (g == 0) {
            const bool hasEdges = (end > beg);
            half8 xv = *reinterpret_cast<const half8*>(x + (size_t)node * K + colh);
            half8 o;
#pragma unroll
            for (int i = 0; i < 8; ++i)
                o[i] = (_Float16)((float)xv[i] + (hasEdges ? (float)acc[i] : 0.0f));
            *reinterpret_cast<half8*>(&sm[wave][colh]) = o;
        }
    }
    __syncthreads();

    // coalesced granule store: threads 4j..4j+3 write one full 64B line of
    // granule j (slots node0..node0+3; node0 % 4 == 0).
    const int t = threadIdx.x;
    if (t < 4 * (K / 8)) {
        const int j = t >> 2, nd = t & 3;
        const int node2 = node0 + nd;
        if (node2 < Nn) {
            half8 o2 = *reinterpret_cast<half8*>(&sm[nd][j * 8]);
            size_t gidx = ((size_t)(node2 >> 6) * (K / 8) + j) * 64 + (node2 & 63);
            *reinterpret_cast<half8*>(xg + gidx * 8) = o2;
        }
    }
}

// ---------------- LDS-free MFMA GEMM from granule layout ----------------
// Block 256 thr = 4 waves arranged RB x CB; wave tile 64x64. A granules and
// Wg granules read straight from global (L1/L2); no LDS, no barriers.

template <int K, int N, int RB, int CB, int OUT_F32, int RELU>
__global__ __launch_bounds__(256) void gemm_g(
    const _Float16* __restrict__ xg, const _Float16* __restrict__ Wg,
    const float* __restrict__ bias, void* __restrict__ C, int Nn)
{
    const int wave = threadIdx.x >> 6;
    const int lane = threadIdx.x & 63;
    const int wr = wave / CB, wc = wave % CB;
    const int rowTile = blockIdx.x * RB + wr;
    const int node0 = rowTile * 64;
    const int r  = lane & 15;
    const int gq = lane >> 4;
    const int cb = wc * 64;

    f32x4 acc[4][4];
#pragma unroll
    for (int mi = 0; mi < 4; ++mi)
#pragma unroll
        for (int ni = 0; ni < 4; ++ni) acc[mi][ni] = (f32x4){0.f, 0.f, 0.f, 0.f};

    const _Float16* Ab = xg + (size_t)rowTile * K * 64;

    for (int k0 = 0; k0 < K; k0 += 32) {
        const int jb = (k0 >> 3) + gq;
        half8 aF[4], bF[4];
#pragma unroll
        for (int mi = 0; mi < 4; ++mi)
            aF[mi] = *reinterpret_cast<const half8*>(Ab + (size_t)((jb << 6) + mi * 16 + r) * 8);
#pragma unroll
        for (int ni = 0; ni < 4; ++ni)
            bF[ni] = *reinterpret_cast<const half8*>(Wg + ((size_t)jb * N + cb + ni * 16 + r) * 8);
#pragma unroll
        for (int mi = 0; mi < 4; ++mi)
#pragma unroll
            for (int ni = 0; ni < 4; ++ni)
                acc[mi][ni] = __builtin_amdgcn_mfma_f32_16x16x32_f16(aF[mi], bF[ni], acc[mi][ni], 0, 0, 0);
    }

#pragma unroll
    for (int ni = 0; ni < 4; ++ni) {
        int colC = cb + ni * 16 + r;
        float bv = bias[colC];
#pragma unroll
        for (int mi = 0; mi < 4; ++mi) {
#pragma unroll
            for (int q = 0; q < 4; ++q) {
                int row = node0 + mi * 16 + (gq << 2) + q;
                if (row < Nn) {
                    float v = acc[mi][ni][q] + bv;
                    if (RELU) v = fmaxf(v, 0.f);
                    if (OUT_F32) ((float*)C)[(size_t)row * N + colC] = v;
                    else         ((_Float16*)C)[(size_t)row * N + colC] = (_Float16)v;
                }
            }
        }
    }
}

// ---------------- launch ----------------

extern "C" void kernel_launch(void* const* d_in, const int* in_sizes, int n_in,
                              void* d_out, int out_size, void* d_ws, size_t ws_size,
                              hipStream_t stream) {
    const int*   src = (const int*)d_in[0];
    const int*   dst = (const int*)d_in[1];
    const float* emb = (const float*)d_in[2];
    const float* W1  = (const float*)d_in[3];
    const float* b1  = (const float*)d_in[4];
    const float* W2  = (const float*)d_in[5];
    const float* b2  = (const float*)d_in[6];
    const float* W3  = (const float*)d_in[7];
    const float* b3  = (const float*)d_in[8];
    float* out = (float*)d_out;

    const int E  = in_sizes[0];
    const int Nn = in_sizes[2] / EMB;
    const int nTiles = (Nn + 63) / 64;

    char* ws = (char*)d_ws;
    auto align256 = [](size_t x) { return (x + 255) & ~(size_t)255; };
    size_t p = 0;
    int* off      = (int*)(ws + p); p = align256(p + (size_t)(Nn + 1) * 4);
    int* cur      = (int*)(ws + p); p = align256(p + (size_t)(Nn + 1) * 4);
    int* partials = (int*)(ws + p); p = align256(p + 256 * 4);
    u16* sorted   = (u16*)(ws + p); p = align256(p + (size_t)E * 2);
    _Float16* buf0 = (_Float16*)(ws + p); p = align256(p + (size_t)Nn * HIDN * 2);
    _Float16* buf1 = (_Float16*)(ws + p); p = align256(p + (size_t)Nn * HIDN * 2);
    _Float16* xg   = (_Float16*)(ws + p); p = align256(p + (size_t)(nTiles + 2) * 64 * HIDN * 2);
    _Float16* Wg1  = (_Float16*)(ws + p); p = align256(p + (size_t)EMB * HIDN * 2);
    _Float16* Wg2  = (_Float16*)(ws + p); p = align256(p + (size_t)HIDN * HIDN * 2);
    _Float16* Wg3  = (_Float16*)(ws + p); p = align256(p + (size_t)HIDN * EMB * 2);

    // ---- zero counters, then fused prep (cvt + hist + W packs) ----
    hipMemsetAsync(cur, 0, (size_t)Nn * 4, stream);
    const int n4 = Nn * EMB / 4;
    const int bCvtEnd  = (n4 + 255) / 256;
    const int bHistEnd = bCvtEnd + (E + 255) / 256;
    const int bW1End   = bHistEnd + (EMB / 8 * HIDN + 255) / 256;
    const int bW2End   = bW1End + (HIDN / 8 * HIDN + 255) / 256;
    const int bW3End   = bW2End + (HIDN / 8 * EMB + 255) / 256;
    prep_kernel<<<bW3End, 256, 0, stream>>>(dst, E, cur, emb, buf0, n4,
                                            W1, Wg1, W2, Wg2, W3, Wg3,
                                            bCvtEnd, bHistEnd, bW1End, bW2End, bW3End);

    // ---- CSR scan + scatter ----
    const int nScanBlocks = (Nn + 1023) / 1024;   // <= 64 supported by scan_apply
    scan_partial<<<nScanBlocks, 256, 0, stream>>>(cur, partials, Nn);
    scan_apply<<<nScanBlocks, 256, 0, stream>>>(cur, partials, nScanBlocks, off, cur, Nn, E);
    scatter_kernel<<<(E + 255) / 256, 256, 0, stream>>>(src, dst, E, cur, sorted);

    const int segBlocks = (Nn + 3) / 4;

    // ---- Layer 1: K=128 -> N=256, relu ----
    segmax_g<128><<<segBlocks, 256, 0, stream>>>(buf0, off, sorted, xg, Nn);
    gemm_g<128, 256, 1, 4, 0, 1><<<nTiles, 256, 0, stream>>>(xg, Wg1, b1, buf1, Nn);

    // ---- Layer 2: K=256 -> N=256, relu ----
    segmax_g<256><<<segBlocks, 256, 0, stream>>>(buf1, off, sorted, xg, Nn);
    gemm_g<256, 256, 1, 4, 0, 1><<<nTiles, 256, 0, stream>>>(xg, Wg2, b2, buf0, Nn);

    // ---- Layer 3: K=256 -> N=128, no relu, f32 out ----
    segmax_g<256><<<segBlocks, 256, 0, stream>>>(buf0, off, sorted, xg, Nn);
    gemm_g<256, 128, 2, 2, 1, 0><<<(nTiles + 1) / 2, 256, 0, stream>>>(xg, Wg3, b3, out, Nn);
}

// Round 11
// 293.572 us; speedup vs baseline: 1.6998x; 1.0332x over previous
//
#include <hip/hip_runtime.h>
#include <math.h>

#define EMB 128
#define HIDN 256

typedef _Float16 half8 __attribute__((ext_vector_type(8)));
typedef _Float16 half4 __attribute__((ext_vector_type(4)));
typedef float f32x4 __attribute__((ext_vector_type(4)));
typedef unsigned short u16;

// ---------------- fused prep: f32->f16 + W granule packing + hist ----------------

__device__ __forceinline__ void pack_w_one(const float* __restrict__ W, _Float16* __restrict__ Wg,
                                           int K, int N, int i) {
    if (i < (K / 8) * N) {
        int j = i / N, n = i - j * N;
        half8 h;
#pragma unroll
        for (int q = 0; q < 8; ++q) h[q] = (_Float16)W[(size_t)(j * 8 + q) * N + n];
        *reinterpret_cast<half8*>(Wg + (size_t)i * 8) = h;
    }
}

__global__ void prep_kernel(const int* __restrict__ dst, int E, int* __restrict__ cur,
                            const float* __restrict__ emb, _Float16* __restrict__ buf0, int n4,
                            const float* __restrict__ W1, _Float16* __restrict__ Wg1,
                            const float* __restrict__ W2, _Float16* __restrict__ Wg2,
                            const float* __restrict__ W3, _Float16* __restrict__ Wg3,
                            int bCvtEnd, int bHistEnd, int bW1End, int bW2End, int bW3End) {
    const int b = blockIdx.x;
    const int t = threadIdx.x;
    if (b < bCvtEnd) {
        int i = b * 256 + t;
        if (i < n4) {
            float4 v = *reinterpret_cast<const float4*>(emb + (size_t)i * 4);
            half4 h;
            h[0] = (_Float16)v.x; h[1] = (_Float16)v.y;
            h[2] = (_Float16)v.z; h[3] = (_Float16)v.w;
            *reinterpret_cast<half4*>(buf0 + (size_t)i * 4) = h;
        }
    } else if (b < bHistEnd) {
        int i = (b - bCvtEnd) * 256 + t;
        if (i < E) atomicAdd(&cur[dst[i]], 1);
    } else if (b < bW1End) {
        pack_w_one(W1, Wg1, EMB, HIDN, (b - bHistEnd) * 256 + t);
    } else if (b < bW2End) {
        pack_w_one(W2, Wg2, HIDN, HIDN, (b - bW1End) * 256 + t);
    } else if (b < bW3End) {
        pack_w_one(W3, Wg3, HIDN, EMB, (b - bW2End) * 256 + t);
    }
}

// ---------------- hierarchical scan (2 kernels) ----------------

__global__ void scan_partial(const int* __restrict__ cnt, int* __restrict__ partials, int Nn) {
    __shared__ int red[256];
    const int b = blockIdx.x, t = threadIdx.x;
    const int base = b * 1024 + t * 4;
    int s = 0;
#pragma unroll
    for (int i = 0; i < 4; ++i)
        if (base + i < Nn) s += cnt[base + i];
    red[t] = s;
    __syncthreads();
    for (int d = 128; d > 0; d >>= 1) {
        if (t < d) red[t] += red[t + d];
        __syncthreads();
    }
    if (t == 0) partials[b] = red[0];
}

__global__ void scan_apply(const int* __restrict__ cnt, const int* __restrict__ partials,
                           int nB, int* __restrict__ off, int* __restrict__ cur, int Nn, int E) {
    __shared__ int tsum[256];
    __shared__ int sbase;
    const int b = blockIdx.x, t = threadIdx.x;
    if (t < 64) {
        int v = (t < b && t < nB) ? partials[t] : 0;
#pragma unroll
        for (int m = 1; m < 64; m <<= 1) v += __shfl_xor(v, m);
        if (t == 0) sbase = v;
    }
    const int base = b * 1024 + t * 4;
    int c[4];
#pragma unroll
    for (int i = 0; i < 4; ++i) c[i] = (base + i < Nn) ? cnt[base + i] : 0;
    int s = c[0] + c[1] + c[2] + c[3];
    tsum[t] = s;
    __syncthreads();
    for (int d = 1; d < 256; d <<= 1) {
        int v = (t >= d) ? tsum[t - d] : 0;
        __syncthreads();
        tsum[t] += v;
        __syncthreads();
    }
    int run = sbase + ((t == 0) ? 0 : tsum[t - 1]);
#pragma unroll
    for (int i = 0; i < 4; ++i) {
        int idx = base + i;
        if (idx < Nn) {
            off[idx] = run;
            cur[idx] = run;
            run += c[i];
        }
    }
    if (b == 0 && t == 0) off[Nn] = E;
}

// Nn < 65536 -> u16 neighbor indices
__global__ void scatter_kernel(const int* __restrict__ src, const int* __restrict__ dst,
                               int E, int* __restrict__ cur, u16* __restrict__ sorted) {
    int i = blockIdx.x * blockDim.x + threadIdx.x;
    if (i < E) {
        int d = dst[i];
        int p = atomicAdd(&cur[d], 1);
        sorted[p] = (u16)src[i];
    }
}

// ---------------- segment-max + self-add -> MFMA granule layout ----------------
// One wave per node (block = 4 waves = 4 nodes). NG = 512/K edge streams.
// 8 clamped loads into NAMED registers (i>=m duplicates last edge; max is
// idempotent; same-address dups are L1 line hits) -> 8 misses in flight per
// wave. Rare deg > 8*NG tail handled by a loop. 3-level max tree.

template <int K>
__global__ __launch_bounds__(256) void segmax_g(
    const _Float16* __restrict__ x, const int* __restrict__ off,
    const u16* __restrict__ sorted, _Float16* __restrict__ xg, int Nn)
{
    constexpr int NG = 512 / K;        // 2 for K=256, 4 for K=128
    constexpr int LPR = 64 / NG;       // lanes per row
    __shared__ _Float16 sm[4][K];

    const int wave = threadIdx.x >> 6;
    const int lane = threadIdx.x & 63;
    const int node0 = blockIdx.x * 4;
    const int node = node0 + wave;

    if (node < Nn) {
        const int g = lane / LPR;
        const int colh = (lane % LPR) * 8;
        const int beg = off[node];
        const int end = off[node + 1];
        const _Float16* xcol = x + colh;

        half8 acc;
#pragma unroll
        for (int i = 0; i < 8; ++i) acc[i] = (_Float16)(-INFINITY);

        const int base = beg + g;
        const int cnt0 = end - base;
        if (cnt0 > 0) {
            const int m = (cnt0 + NG - 1) / NG;   // iterations for this stream
            const int mm = m - 1;
            half8 v[8];
#pragma unroll
            for (int i = 0; i < 8; ++i) {
                const int ii = (i < mm) ? i : mm;            // clamp; dup for i>=m
                const int s = (int)sorted[base + ii * NG];
                v[i] = *reinterpret_cast<const half8*>(xcol + (size_t)s * K);
            }
            // rare tail: deg > 8*NG
            for (int i = 8; i < m; ++i) {
                const int s = (int)sorted[base + i * NG];
                half8 w = *reinterpret_cast<const half8*>(xcol + (size_t)s * K);
                acc = __builtin_elementwise_max(acc, w);
            }
            // 3-level tree
            v[0] = __builtin_elementwise_max(v[0], v[4]);
            v[1] = __builtin_elementwise_max(v[1], v[5]);
            v[2] = __builtin_elementwise_max(v[2], v[6]);
            v[3] = __builtin_elementwise_max(v[3], v[7]);
            v[0] = __builtin_elementwise_max(v[0], v[2]);
            v[1] = __builtin_elementwise_max(v[1], v[3]);
            acc  = __builtin_elementwise_max(acc, __builtin_elementwise_max(v[0], v[1]));
        }

        // combine edge streams (lanes with same colh)
        union U { half8 h; int i[4]; };
        if (NG == 4) {
            U a, b; a.h = acc;
#pragma unroll
            for (int k = 0; k < 4; ++k) b.i[k] = __shfl_xor(a.i[k], 16);
            acc = __builtin_elementwise_max(a.h, b.h);
        }
        {
            U a, b; a.h = acc;
#pragma unroll
            for (int k = 0; k < 4; ++k) b.i[k] = __shfl_xor(a.i[k], 32);
            acc = __builtin_elementwise_max(a.h, b.h);
        }

        if (g == 0) {
            const bool hasEdges = (end > beg);
            half8 xv = *reinterpret_cast<const half8*>(x + (size_t)node * K + colh);
            half8 o;
#pragma unroll
            for (int i = 0; i < 8; ++i)
                o[i] = (_Float16)((float)xv[i] + (hasEdges ? (float)acc[i] : 0.0f));
            *reinterpret_cast<half8*>(&sm[wave][colh]) = o;
        }
    }
    __syncthreads();

    // coalesced granule store: threads 4j..4j+3 write one full 64B line of
    // granule j (slots node0..node0+3; node0 % 4 == 0).
    const int t = threadIdx.x;
    if (t < 4 * (K / 8)) {
        const int j = t >> 2, nd = t & 3;
        const int node2 = node0 + nd;
        if (node2 < Nn) {
            half8 o2 = *reinterpret_cast<half8*>(&sm[nd][j * 8]);
            size_t gidx = ((size_t)(node2 >> 6) * (K / 8) + j) * 64 + (node2 & 63);
            *reinterpret_cast<half8*>(xg + gidx * 8) = o2;
        }
    }
}

// ---------------- LDS-free MFMA GEMM from granule layout ----------------

template <int K, int N, int RB, int CB, int OUT_F32, int RELU>
__global__ __launch_bounds__(256) void gemm_g(
    const _Float16* __restrict__ xg, const _Float16* __restrict__ Wg,
    const float* __restrict__ bias, void* __restrict__ C, int Nn)
{
    const int wave = threadIdx.x >> 6;
    const int lane = threadIdx.x & 63;
    const int wr = wave / CB, wc = wave % CB;
    const int rowTile = blockIdx.x * RB + wr;
    const int node0 = rowTile * 64;
    const int r  = lane & 15;
    const int gq = lane >> 4;
    const int cb = wc * 64;

    f32x4 acc[4][4];
#pragma unroll
    for (int mi = 0; mi < 4; ++mi)
#pragma unroll
        for (int ni = 0; ni < 4; ++ni) acc[mi][ni] = (f32x4){0.f, 0.f, 0.f, 0.f};

    const _Float16* Ab = xg + (size_t)rowTile * K * 64;

    for (int k0 = 0; k0 < K; k0 += 32) {
        const int jb = (k0 >> 3) + gq;
        half8 aF[4], bF[4];
#pragma unroll
        for (int mi = 0; mi < 4; ++mi)
            aF[mi] = *reinterpret_cast<const half8*>(Ab + (size_t)((jb << 6) + mi * 16 + r) * 8);
#pragma unroll
        for (int ni = 0; ni < 4; ++ni)
            bF[ni] = *reinterpret_cast<const half8*>(Wg + ((size_t)jb * N + cb + ni * 16 + r) * 8);
#pragma unroll
        for (int mi = 0; mi < 4; ++mi)
#pragma unroll
            for (int ni = 0; ni < 4; ++ni)
                acc[mi][ni] = __builtin_amdgcn_mfma_f32_16x16x32_f16(aF[mi], bF[ni], acc[mi][ni], 0, 0, 0);
    }

#pragma unroll
    for (int ni = 0; ni < 4; ++ni) {
        int colC = cb + ni * 16 + r;
        float bv = bias[colC];
#pragma unroll
        for (int mi = 0; mi < 4; ++mi) {
#pragma unroll
            for (int q = 0; q < 4; ++q) {
                int row = node0 + mi * 16 + (gq << 2) + q;
                if (row < Nn) {
                    float v = acc[mi][ni][q] + bv;
                    if (RELU) v = fmaxf(v, 0.f);
                    if (OUT_F32) ((float*)C)[(size_t)row * N + colC] = v;
                    else         ((_Float16*)C)[(size_t)row * N + colC] = (_Float16)v;
                }
            }
        }
    }
}

// ---------------- launch ----------------

extern "C" void kernel_launch(void* const* d_in, const int* in_sizes, int n_in,
                              void* d_out, int out_size, void* d_ws, size_t ws_size,
                              hipStream_t stream) {
    const int*   src = (const int*)d_in[0];
    const int*   dst = (const int*)d_in[1];
    const float* emb = (const float*)d_in[2];
    const float* W1  = (const float*)d_in[3];
    const float* b1  = (const float*)d_in[4];
    const float* W2  = (const float*)d_in[5];
    const float* b2  = (const float*)d_in[6];
    const float* W3  = (const float*)d_in[7];
    const float* b3  = (const float*)d_in[8];
    float* out = (float*)d_out;

    const int E  = in_sizes[0];
    const int Nn = in_sizes[2] / EMB;
    const int nTiles = (Nn + 63) / 64;

    char* ws = (char*)d_ws;
    auto align256 = [](size_t x) { return (x + 255) & ~(size_t)255; };
    size_t p = 0;
    int* off      = (int*)(ws + p); p = align256(p + (size_t)(Nn + 1) * 4);
    int* cur      = (int*)(ws + p); p = align256(p + (size_t)(Nn + 1) * 4);
    int* partials = (int*)(ws + p); p = align256(p + 256 * 4);
    u16* sorted   = (u16*)(ws + p); p = align256(p + (size_t)E * 2);
    _Float16* buf0 = (_Float16*)(ws + p); p = align256(p + (size_t)Nn * HIDN * 2);
    _Float16* buf1 = (_Float16*)(ws + p); p = align256(p + (size_t)Nn * HIDN * 2);
    _Float16* xg   = (_Float16*)(ws + p); p = align256(p + (size_t)(nTiles + 2) * 64 * HIDN * 2);
    _Float16* Wg1  = (_Float16*)(ws + p); p = align256(p + (size_t)EMB * HIDN * 2);
    _Float16* Wg2  = (_Float16*)(ws + p); p = align256(p + (size_t)HIDN * HIDN * 2);
    _Float16* Wg3  = (_Float16*)(ws + p); p = align256(p + (size_t)HIDN * EMB * 2);

    // ---- zero counters, then fused prep (cvt + hist + W packs) ----
    hipMemsetAsync(cur, 0, (size_t)Nn * 4, stream);
    const int n4 = Nn * EMB / 4;
    const int bCvtEnd  = (n4 + 255) / 256;
    const int bHistEnd = bCvtEnd + (E + 255) / 256;
    const int bW1End   = bHistEnd + (EMB / 8 * HIDN + 255) / 256;
    const int bW2End   = bW1End + (HIDN / 8 * HIDN + 255) / 256;
    const int bW3End   = bW2End + (HIDN / 8 * EMB + 255) / 256;
    prep_kernel<<<bW3End, 256, 0, stream>>>(dst, E, cur, emb, buf0, n4,
                                            W1, Wg1, W2, Wg2, W3, Wg3,
                                            bCvtEnd, bHistEnd, bW1End, bW2End, bW3End);

    // ---- CSR scan + scatter ----
    const int nScanBlocks = (Nn + 1023) / 1024;   // <= 64 supported by scan_apply
    scan_partial<<<nScanBlocks, 256, 0, stream>>>(cur, partials, Nn);
    scan_apply<<<nScanBlocks, 256, 0, stream>>>(cur, partials, nScanBlocks, off, cur, Nn, E);
    scatter_kernel<<<(E + 255) / 256, 256, 0, stream>>>(src, dst, E, cur, sorted);

    const int segBlocks = (Nn + 3) / 4;

    // ---- Layer 1: K=128 -> N=256, relu ----
    segmax_g<128><<<segBlocks, 256, 0, stream>>>(buf0, off, sorted, xg, Nn);
    gemm_g<128, 256, 1, 4, 0, 1><<<nTiles, 256, 0, stream>>>(xg, Wg1, b1, buf1, Nn);

    // ---- Layer 2: K=256 -> N=256, relu ----
    segmax_g<256><<<segBlocks, 256, 0, stream>>>(buf1, off, sorted, xg, Nn);
    gemm_g<256, 256, 1, 4, 0, 1><<<nTiles, 256, 0, stream>>>(xg, Wg2, b2, buf0, Nn);

    // ---- Layer 3: K=256 -> N=128, no relu, f32 out ----
    segmax_g<256><<<segBlocks, 256, 0, stream>>>(buf0, off, sorted, xg, Nn);
    gemm_g<256, 128, 2, 2, 1, 0><<<(nTiles + 1) / 2, 256, 0, stream>>>(xg, Wg3, b3, out, Nn);
}